// Round 3
// baseline (423.852 us; speedup 1.0000x reference)
//
#include <hip/hip_runtime.h>
#include <math.h>

#define BB 32
#define MM 2048
#define KK 4
#define EE 128
#define GG 128
#define VV 50000
#define HOPS 3

// ---------------- GRU cell: one block per batch row ----------------
__global__ __launch_bounds__(384) void gru_kernel(
    const float* __restrict__ emb0,   // emb table 0 [V][E]
    const int*   __restrict__ y,      // [B]
    const float* __restrict__ hprev,  // [B][G]
    const float* __restrict__ W_ih,   // [3G][E]
    const float* __restrict__ W_hh,   // [3G][G]
    const float* __restrict__ b_ih,   // [3G]
    const float* __restrict__ b_hh,   // [3G]
    float* __restrict__ h_out,        // d_out [B][G]
    float* __restrict__ q)            // ws    [B][G]
{
    int b = blockIdx.x;
    int t = threadIdx.x;
    __shared__ float x[EE], h[GG], gi[3*GG], gh[3*GG];
    if (t < EE)            x[t]       = emb0[(size_t)y[b]*EE + t];
    else if (t < 2*EE)     h[t-EE]    = hprev[b*GG + (t-EE)];
    __syncthreads();
    {
        float accI = b_ih[t], accH = b_hh[t];
        const float* wi = W_ih + (size_t)t*EE;
        const float* wh = W_hh + (size_t)t*GG;
        #pragma unroll 8
        for (int e = 0; e < EE; e++) { accI += x[e]*wi[e]; accH += h[e]*wh[e]; }
        gi[t] = accI; gh[t] = accH;
    }
    __syncthreads();
    if (t < GG) {
        float r = 1.f/(1.f + __expf(-(gi[t]        + gh[t])));
        float z = 1.f/(1.f + __expf(-(gi[GG+t]     + gh[GG+t])));
        float n = tanhf(gi[2*GG+t] + r*gh[2*GG+t]);
        float hn = (1.f - z)*n + z*h[t];
        h_out[b*GG + t] = hn;
        q[b*GG + t]     = hn;
    }
}

// ---------------- d[b][v] = q[b] . emb[v]  (50000x32x128 GEMM, streams table once) ----
__global__ __launch_bounds__(256) void dvec_kernel(
    const float* __restrict__ q,      // [B][128]
    const float* __restrict__ W,      // emb table [V][128]
    float* __restrict__ d)            // [B][V]
{
    __shared__ float Ut[128][32];     // [e][b] 16 KB
    __shared__ float Wt[32][132];     // [e_local][v_local] 16.9 KB
    int t = threadIdx.x;
    for (int i = t; i < 128*32; i += 256) {
        int e = i >> 5, b = i & 31;
        Ut[e][b] = q[b*EE + e];
    }
    int vg = t & 31;        // 32 v-groups of 4
    int bg = t >> 5;        // 8 b-groups of 4
    int v0 = blockIdx.x * 128;
    float acc[4][4];
    #pragma unroll
    for (int i = 0; i < 4; i++)
        #pragma unroll
        for (int j = 0; j < 4; j++) acc[i][j] = 0.f;

    int vrow = t >> 1;
    int half = t & 1;
    const float* wrow = W + (size_t)(v0 + vrow)*128 + half*16;
    bool vok = (v0 + vrow) < VV;

    for (int ec = 0; ec < 128; ec += 32) {
        __syncthreads();
        #pragma unroll
        for (int j = 0; j < 4; j++) {
            float4 w = make_float4(0.f, 0.f, 0.f, 0.f);
            if (vok) w = *(const float4*)(wrow + ec + j*4);
            int e0 = half*16 + j*4;
            Wt[e0+0][vrow] = w.x;
            Wt[e0+1][vrow] = w.y;
            Wt[e0+2][vrow] = w.z;
            Wt[e0+3][vrow] = w.w;
        }
        __syncthreads();
        #pragma unroll 8
        for (int e = 0; e < 32; e++) {
            float4 w = *(const float4*)(&Wt[e][vg*4]);
            float4 u = *(const float4*)(&Ut[ec + e][bg*4]);
            acc[0][0] += w.x*u.x; acc[0][1] += w.x*u.y; acc[0][2] += w.x*u.z; acc[0][3] += w.x*u.w;
            acc[1][0] += w.y*u.x; acc[1][1] += w.y*u.y; acc[1][2] += w.y*u.z; acc[1][3] += w.y*u.w;
            acc[2][0] += w.z*u.x; acc[2][1] += w.z*u.y; acc[2][2] += w.z*u.z; acc[2][3] += w.z*u.w;
            acc[3][0] += w.w*u.x; acc[3][1] += w.w*u.y; acc[3][2] += w.w*u.z; acc[3][3] += w.w*u.w;
        }
    }
    #pragma unroll
    for (int i = 0; i < 4; i++) {
        int v = v0 + vg*4 + i;
        if (v < VV) {
            #pragma unroll
            for (int j = 0; j < 4; j++)
                d[(size_t)(bg*4 + j)*VV + v] = acc[i][j];
        }
    }
}

// ---------------- scores via d-gather + softmax over M, fused: one block per b --------
__global__ __launch_bounds__(256) void attn_kernel(
    const float* __restrict__ d,      // [B][V]
    const int*   __restrict__ ctx,    // [B][M][K]
    float* __restrict__ attn)         // [B][M] dest
{
    int b = blockIdx.x, t = threadIdx.x;
    const float* db = d + (size_t)b*VV;
    float v[8];
    float mx = -INFINITY;
    #pragma unroll
    for (int i = 0; i < 8; i++) {
        int m = t + i*256;
        const int4 c = *(const int4*)(ctx + (size_t)(b*MM + m)*KK);
        v[i] = db[c.x] + db[c.y] + db[c.z] + db[c.w];
        mx = fmaxf(mx, v[i]);
    }
    __shared__ float red[6];
    int w = t >> 6, lane = t & 63;
    #pragma unroll
    for (int off = 32; off; off >>= 1) mx = fmaxf(mx, __shfl_down(mx, off));
    if (lane == 0) red[w] = mx;
    __syncthreads();
    if (t == 0) { red[4] = fmaxf(fmaxf(red[0],red[1]), fmaxf(red[2],red[3])); }
    __syncthreads();
    mx = red[4];
    float sum = 0.f;
    #pragma unroll
    for (int i = 0; i < 8; i++) { v[i] = __expf(v[i] - mx); sum += v[i]; }
    #pragma unroll
    for (int off = 32; off; off >>= 1) sum += __shfl_down(sum, off);
    if (lane == 0) red[w] = sum;
    __syncthreads();
    if (t == 0) { red[5] = 1.f / (red[0]+red[1]+red[2]+red[3]); }
    __syncthreads();
    float rs = red[5];
    #pragma unroll
    for (int i = 0; i < 8; i++) attn[(size_t)b*MM + t + i*256] = v[i]*rs;
}

// ---------------- zero the scatter accumulator ----------------
__global__ __launch_bounds__(256) void zero_kernel(float* __restrict__ w, int n4)
{
    int i = blockIdx.x*256 + threadIdx.x;
    if (i < n4) ((float4*)w)[i] = make_float4(0.f,0.f,0.f,0.f);
}

// ---------------- scatter attn weights into w[b][v] ----------------
__global__ __launch_bounds__(256) void scatter_kernel(
    const float* __restrict__ attn,   // [B][M]
    const int*   __restrict__ ctx,    // [B][M][K]
    float* __restrict__ w)            // [B][V]
{
    int gid = blockIdx.x*256 + threadIdx.x;    // over B*M = 65536
    float a = attn[gid];
    int b = gid >> 11;
    const int4 c = *(const int4*)(ctx + (size_t)gid*KK);
    float* wb = w + (size_t)b*VV;
    atomicAdd(&wb[c.x], a);
    atomicAdd(&wb[c.y], a);
    atomicAdd(&wb[c.z], a);
    atomicAdd(&wb[c.w], a);
}

// ---------------- o_part[s][b][e] = sum_{v in chunk s} w[b][v] * emb[v][e] ------------
#define OCH 196   // ceil(50000/256)
__global__ __launch_bounds__(256) void oaccv_kernel(
    const float* __restrict__ emb,    // table h+1 [V][128]
    const float* __restrict__ w,      // [B][V]
    float* __restrict__ o_part)       // [256][B][128]
{
    __shared__ float embS[64][128];   // 32 KB
    __shared__ float wS[64][32];      // 8 KB
    int t = threadIdx.x;
    int bg = t >> 6;                  // wave id: 4 b-groups of 8
    int eg = t & 63;                  // 64 e-groups of 2
    int v0 = blockIdx.x * OCH;
    int vend = min(v0 + OCH, VV);
    float acc[8][2];
    #pragma unroll
    for (int j = 0; j < 8; j++) { acc[j][0] = 0.f; acc[j][1] = 0.f; }

    for (int vs = v0; vs < vend; vs += 64) {
        int nv = vend - vs; if (nv > 64) nv = 64;
        __syncthreads();
        // stage emb rows [nv][128] (2048 float4, 8 per thread)
        for (int i = t; i < 64*32; i += 256) {
            int row = i >> 5, c4 = i & 31;
            float4 val = make_float4(0.f,0.f,0.f,0.f);
            if (row < nv) val = *(const float4*)(emb + (size_t)(vs+row)*128 + c4*4);
            *(float4*)(&embS[row][c4*4]) = val;
        }
        // stage w [32 b][64 v] transposed into wS[v][b] (512 float4, 2 per thread)
        for (int i = t; i < 512; i += 256) {
            int b = i >> 4, vv = (i & 15)*4;
            float4 val = make_float4(0.f,0.f,0.f,0.f);
            if (vv < nv) val = *(const float4*)(w + (size_t)b*VV + vs + vv);
            wS[vv+0][b] = val.x; wS[vv+1][b] = val.y;
            wS[vv+2][b] = val.z; wS[vv+3][b] = val.w;
        }
        __syncthreads();
        for (int vv = 0; vv < nv; vv++) {
            float2 ev = *(const float2*)(&embS[vv][eg*2]);
            float4 w0 = *(const float4*)(&wS[vv][bg*8]);
            float4 w1 = *(const float4*)(&wS[vv][bg*8+4]);
            acc[0][0] += w0.x*ev.x; acc[0][1] += w0.x*ev.y;
            acc[1][0] += w0.y*ev.x; acc[1][1] += w0.y*ev.y;
            acc[2][0] += w0.z*ev.x; acc[2][1] += w0.z*ev.y;
            acc[3][0] += w0.w*ev.x; acc[3][1] += w0.w*ev.y;
            acc[4][0] += w1.x*ev.x; acc[4][1] += w1.x*ev.y;
            acc[5][0] += w1.y*ev.x; acc[5][1] += w1.y*ev.y;
            acc[6][0] += w1.z*ev.x; acc[6][1] += w1.z*ev.y;
            acc[7][0] += w1.w*ev.x; acc[7][1] += w1.w*ev.y;
        }
    }
    float* op = o_part + (size_t)blockIdx.x*BB*EE;
    #pragma unroll
    for (int j = 0; j < 8; j++) {
        op[(bg*8+j)*EE + eg*2]     = acc[j][0];
        op[(bg*8+j)*EE + eg*2 + 1] = acc[j][1];
    }
}

// ---------------- q update (and o1 save): reduce 256 partials ----------------
__global__ __launch_bounds__(256) void qupd_kernel(
    const float* __restrict__ o_part, // [256][B][E]
    float* __restrict__ q,            // [B][E]
    float* __restrict__ o1,
    int save_o1)
{
    int i = blockIdx.x*256 + threadIdx.x;   // over B*E = 4096
    float v = 0.f;
    #pragma unroll 8
    for (int s = 0; s < 256; s++) v += o_part[(size_t)s*BB*EE + i];
    q[i] += v;
    if (save_o1) o1[i] = v;
}

// ---------------- vocab logits: 50000x32x256 GEMM, 4v x 4b register tile ----------------
__global__ __launch_bounds__(256) void logits_kernel(
    const float* __restrict__ h,      // [B][G] (from d_out)
    const float* __restrict__ o1,     // [B][E] (ws)
    const float* __restrict__ Wv,     // [V][256]
    const float* __restrict__ bv,     // [V]
    float* __restrict__ logits)       // [B][V] (d_out p_vocab region)
{
    __shared__ float Ut[256][32];     // [e][b]
    __shared__ float Wt[32][132];     // [e_local][v_local]
    int t = threadIdx.x;
    for (int i = t; i < 256*32; i += 256) {
        int e = i >> 5, b = i & 31;
        Ut[e][b] = (e < GG) ? h[b*GG + e] : o1[b*EE + (e - GG)];
    }
    int vg = t & 31;
    int bg = t >> 5;
    int v0 = blockIdx.x * 128;
    float acc[4][4];
    #pragma unroll
    for (int i = 0; i < 4; i++)
        #pragma unroll
        for (int j = 0; j < 4; j++) acc[i][j] = 0.f;

    int vrow = t >> 1;
    int half = t & 1;
    const float* wrow = Wv + (size_t)(v0 + vrow)*256 + half*16;
    bool vok = (v0 + vrow) < VV;

    for (int ec = 0; ec < 256; ec += 32) {
        __syncthreads();
        #pragma unroll
        for (int j = 0; j < 4; j++) {
            float4 w = make_float4(0.f, 0.f, 0.f, 0.f);
            if (vok) w = *(const float4*)(wrow + ec + j*4);
            int e0 = half*16 + j*4;
            Wt[e0+0][vrow] = w.x;
            Wt[e0+1][vrow] = w.y;
            Wt[e0+2][vrow] = w.z;
            Wt[e0+3][vrow] = w.w;
        }
        __syncthreads();
        #pragma unroll 8
        for (int e = 0; e < 32; e++) {
            float4 w = *(const float4*)(&Wt[e][vg*4]);
            float4 u = *(const float4*)(&Ut[ec + e][bg*4]);
            acc[0][0] += w.x*u.x; acc[0][1] += w.x*u.y; acc[0][2] += w.x*u.z; acc[0][3] += w.x*u.w;
            acc[1][0] += w.y*u.x; acc[1][1] += w.y*u.y; acc[1][2] += w.y*u.z; acc[1][3] += w.y*u.w;
            acc[2][0] += w.z*u.x; acc[2][1] += w.z*u.y; acc[2][2] += w.z*u.z; acc[2][3] += w.z*u.w;
            acc[3][0] += w.w*u.x; acc[3][1] += w.w*u.y; acc[3][2] += w.w*u.z; acc[3][3] += w.w*u.w;
        }
    }
    #pragma unroll
    for (int i = 0; i < 4; i++) {
        int v = v0 + vg*4 + i;
        if (v < VV) {
            float bb = bv[v];
            #pragma unroll
            for (int j = 0; j < 4; j++)
                logits[(size_t)(bg*4 + j)*VV + v] = acc[i][j] + bb;
        }
    }
}

// ---------------- vocab softmax partial stats: 8 chunks per batch row ----------------
#define VCHUNK 6250
__global__ __launch_bounds__(256) void vpart_kernel(
    const float* __restrict__ logits, // [B][V]
    float* __restrict__ part)         // [B][8][2] = {max, sumexp}
{
    int blk = blockIdx.x;             // b*8 + c
    int b = blk >> 3, c = blk & 7;
    int t = threadIdx.x;
    const float* row = logits + (size_t)b*VV;
    int start = c*VCHUNK;
    int end   = min(start + VCHUNK, VV);
    __shared__ float red[4];
    int w = t >> 6, lane = t & 63;
    float mx = -INFINITY;
    for (int i = start + t; i < end; i += 256) mx = fmaxf(mx, row[i]);
    #pragma unroll
    for (int off = 32; off; off >>= 1) mx = fmaxf(mx, __shfl_down(mx, off));
    if (lane == 0) red[w] = mx;
    __syncthreads();
    float m = fmaxf(fmaxf(red[0], red[1]), fmaxf(red[2], red[3]));
    float sum = 0.f;
    for (int i = start + t; i < end; i += 256) sum += __expf(row[i] - m);
    #pragma unroll
    for (int off = 32; off; off >>= 1) sum += __shfl_down(sum, off);
    __syncthreads();
    if (lane == 0) red[w] = sum;
    __syncthreads();
    if (t == 0) {
        part[blk*2]   = m;
        part[blk*2+1] = red[0] + red[1] + red[2] + red[3];
    }
}

// ---------------- finalize p_vocab in place ----------------
__global__ __launch_bounds__(256) void vfinal_kernel(
    float* __restrict__ logits,       // [B][V], in-place
    const float* __restrict__ part)   // [B][8][2]
{
    int i = blockIdx.x*256 + threadIdx.x;
    if (i >= BB*VV) return;
    int b = i / VV;
    const float* pp = part + b*16;
    float M = -INFINITY;
    #pragma unroll
    for (int c = 0; c < 8; c++) M = fmaxf(M, pp[c*2]);
    float S = 0.f;
    #pragma unroll
    for (int c = 0; c < 8; c++) S += pp[c*2+1] * __expf(pp[c*2] - M);
    logits[i] = __expf(logits[i] - M) * (1.f / S);
}

extern "C" void kernel_launch(void* const* d_in, const int* in_sizes, int n_in,
                              void* d_out, int out_size, void* d_ws, size_t ws_size,
                              hipStream_t stream) {
    const int*   ctx    = (const int*)  d_in[0];
    const float* h_prev = (const float*)d_in[1];
    const int*   y      = (const int*)  d_in[2];
    const float* emb    = (const float*)d_in[3];
    const float* W_ih   = (const float*)d_in[4];
    const float* W_hh   = (const float*)d_in[5];
    const float* b_ih   = (const float*)d_in[6];
    const float* b_hh   = (const float*)d_in[7];
    const float* Wv     = (const float*)d_in[8];
    const float* bv     = (const float*)d_in[9];

    float* out_h    = (float*)d_out;                 // [B][G]
    float* out_pv   = out_h + BB*GG;                 // [B][V]
    float* out_attn = out_pv + (size_t)BB*VV;        // [B][M]

    float* ws     = (float*)d_ws;
    float* q      = ws;                        // 4096
    float* o1     = q + BB*EE;                 // 4096
    float* d      = o1 + BB*EE;                // B*V = 1.6M
    float* w      = d + (size_t)BB*VV;         // B*V = 1.6M
    float* o_part = w + (size_t)BB*VV;         // 256*4096 = 1M
    float* attn   = o_part + 256*BB*EE;        // 65536
    float* part   = attn + BB*MM;              // 512

    const int dvec_grid = (VV + 127)/128;      // 391
    const int w4 = (BB*VV)/4;                  // 400000 float4s

    gru_kernel<<<BB, 384, 0, stream>>>(emb, y, h_prev, W_ih, W_hh, b_ih, b_hh, out_h, q);

    for (int hop = 0; hop < HOPS; hop++) {
        const float* embA = emb + (size_t)hop*VV*EE;
        dvec_kernel<<<dvec_grid, 256, 0, stream>>>(q, embA, d);
        float* attn_dst = (hop == HOPS-1) ? out_attn : attn;
        attn_kernel<<<BB, 256, 0, stream>>>(d, ctx, attn_dst);
        if (hop == HOPS-1) break;              // o, q-update dead after last hop
        const float* embC = emb + (size_t)(hop+1)*VV*EE;
        zero_kernel<<<(w4 + 255)/256, 256, 0, stream>>>(w, w4);
        scatter_kernel<<<(BB*MM)/256, 256, 0, stream>>>(attn_dst, ctx, w);
        oaccv_kernel<<<256, 256, 0, stream>>>(embC, w, o_part);
        qupd_kernel<<<(BB*EE)/256, 256, 0, stream>>>(o_part, q, o1, hop == 0 ? 1 : 0);
    }

    logits_kernel<<<(VV + 127)/128, 256, 0, stream>>>(out_h, o1, Wv, bv, out_pv);
    vpart_kernel<<<BB*8, 256, 0, stream>>>(out_pv, part);
    vfinal_kernel<<<(BB*VV + 255)/256, 256, 0, stream>>>(out_pv, part);
}